// Round 6
// baseline (289.726 us; speedup 1.0000x reference)
//
#include <hip/hip_runtime.h>
#include <hip/hip_bf16.h>

typedef __hip_bfloat16 bf16;
typedef __attribute__((ext_vector_type(8))) short short8;
typedef __attribute__((ext_vector_type(4))) float f32x4;

#define MFMA16(A, B, C) __builtin_amdgcn_mfma_f32_16x16x32_bf16((A), (B), (C), 0, 0, 0)

__device__ __forceinline__ unsigned pkbf(float a, float b) {
    __hip_bfloat162 h = __float22bfloat162_rn(make_float2(a, b));
    return *reinterpret_cast<unsigned*>(&h);
}

// ---------------- prep: W fp32 -> frag-major bf16 in ws ----------------
__global__ __launch_bounds__(256) void prep_w(const float* __restrict__ wq,
                                              const float* __restrict__ wk,
                                              const float* __restrict__ wv,
                                              bf16* __restrict__ wsW)
{
    const int t = (int)blockIdx.x * 256 + (int)threadIdx.x;   // 0..24575
    const int lane = t & 63, kk = (t >> 6) & 7, mt = (t >> 9) & 15, proj = t >> 13;
    const float* W = (proj == 0) ? wq : ((proj == 1) ? wk : wv);
    const int row = mt * 16 + (lane & 15);
    const int col = kk * 32 + (lane >> 4) * 8;
    bf16* dst = wsW + (size_t)t * 8;
#pragma unroll
    for (int j = 0; j < 8; ++j) dst[j] = __float2bfloat16(W[row * 256 + col + j]);
}

// ---------------- kernel A: projections -> Qw/Kw/Vw (bf16), reg-shuffle epilogues ----
__global__ __launch_bounds__(512, 4)
void projA(const float* __restrict__ x,
           const float* __restrict__ bq, const float* __restrict__ bk,
           const float* __restrict__ bv,
           const bf16* __restrict__ wsW,
           bf16* __restrict__ qw, bf16* __restrict__ kw, bf16* __restrict__ vw,
           int b_base, int nwg)
{
    __shared__ __align__(16) bf16 Xs[64][264];     // 33792 B only

    const int tid = (int)threadIdx.x;
    const int l = tid & 63, w = tid >> 6, h = l >> 4, c15 = l & 15;
    const int chunk = nwg >> 3;
    const int wg = ((int)blockIdx.x & 7) * chunk + ((int)blockIdx.x >> 3);
    const int b = b_base + (wg >> 9), p0 = (wg & 511) * 8;
    const short8* wsv = (const short8*)wsW;

    // ---- stage X -> Xs bf16 (conflict-free pattern, verified R2-R5) ----
    const int p2 = (l & 3) * 2, chi = l >> 2;
    {
        float2 xv[16];
#pragma unroll
        for (int i = 0; i < 16; ++i) {
            const int c = i * 16 + chi;
            xv[i] = *(const float2*)&x[((size_t)((b * 8 + w) * 256 + c)) * 4096 + p0 + p2];
        }
#pragma unroll
        for (int i = 0; i < 16; ++i) {
            const int c = i * 16 + chi;
            Xs[w * 8 + p2][c]     = __float2bfloat16(xv[i].x);
            Xs[w * 8 + p2 + 1][c] = __float2bfloat16(xv[i].y);
        }
    }
    __syncthreads();   // the ONLY barrier

    const int p = c15 & 7, beta = c15 >> 3;
    const size_t tb = (size_t)wg * 16384;

    f32x4 acc0[4], acc1[4];
    short8 wf0[8], wf1[8];

    // ================= Q : wave owns m-tiles {2w, 2w+1} =================
#pragma unroll
    for (int kk = 0; kk < 8; ++kk) {
        wf0[kk] = wsv[((0 * 16 + 2 * w) * 8 + kk) * 64 + l];
        wf1[kk] = wsv[((0 * 16 + 2 * w + 1) * 8 + kk) * 64 + l];
    }
#pragma unroll
    for (int nt = 0; nt < 4; ++nt) { acc0[nt] = (f32x4){0,0,0,0}; acc1[nt] = (f32x4){0,0,0,0}; }
#pragma unroll
    for (int nt = 0; nt < 4; ++nt)
#pragma unroll
        for (int kk = 0; kk < 8; ++kk) {
            const short8 bx = *(const short8*)&Xs[nt * 16 + c15][kk * 32 + h * 8];
            acc0[nt] = MFMA16(wf0[kk], bx, acc0[nt]);
            acc1[nt] = MFMA16(wf1[kk], bx, acc1[nt]);
        }
    {
        const float4 b0 = *(const float4*)&bq[(2 * w) * 16 + 4 * h];
        const float4 b1 = *(const float4*)&bq[(2 * w + 1) * 16 + 4 * h];
        const float b0v[4] = {b0.x, b0.y, b0.z, b0.w}, b1v[4] = {b1.x, b1.y, b1.z, b1.w};
#pragma unroll
        for (int r = 0; r < 4; ++r) {
            unsigned wds[4];
#pragma unroll
            for (int nt = 0; nt < 4; ++nt) {
                const float a0 = acc0[nt][r] + b0v[r];
                const float a1 = acc1[nt][r] + b1v[r];
                const float send = beta ? a0 : a1;          // partner needs acc[my_mi^1]
                const float recv = __shfl_xor(send, 8);
                const float own  = beta ? a1 : a0;          // my output mi = beta
                const float e0 = beta ? recv : own;         // j even (s' even)
                const float e1 = beta ? own  : recv;        // j odd
                wds[nt] = pkbf(e0, e1);
            }
            const int G = 16 * beta + 4 * h + r;            // a-group; s = w
            *(uint4*)(qw + tb + (size_t)((p * 8 + w) * 256 + G * 8)) =
                make_uint4(wds[0], wds[1], wds[2], wds[3]);
        }
    }

    // ================= K : wave owns m-tiles {2w, 2w+1} =================
#pragma unroll
    for (int kk = 0; kk < 8; ++kk) {
        wf0[kk] = wsv[((1 * 16 + 2 * w) * 8 + kk) * 64 + l];
        wf1[kk] = wsv[((1 * 16 + 2 * w + 1) * 8 + kk) * 64 + l];
    }
#pragma unroll
    for (int nt = 0; nt < 4; ++nt) { acc0[nt] = (f32x4){0,0,0,0}; acc1[nt] = (f32x4){0,0,0,0}; }
#pragma unroll
    for (int nt = 0; nt < 4; ++nt)
#pragma unroll
        for (int kk = 0; kk < 8; ++kk) {
            const short8 bx = *(const short8*)&Xs[nt * 16 + c15][kk * 32 + h * 8];
            acc0[nt] = MFMA16(wf0[kk], bx, acc0[nt]);
            acc1[nt] = MFMA16(wf1[kk], bx, acc1[nt]);
        }
    {
        const float4 b0 = *(const float4*)&bk[(2 * w) * 16 + 4 * h];
        const float4 b1 = *(const float4*)&bk[(2 * w + 1) * 16 + 4 * h];
        const float b0v[4] = {b0.x, b0.y, b0.z, b0.w}, b1v[4] = {b1.x, b1.y, b1.z, b1.w};
        const bool lower = (h < 2);
#pragma unroll
        for (int r = 0; r < 4; ++r) {
            const int t = 4 * (h & 1) + r;                  // this pair's t
#pragma unroll
            for (int nt = 0; nt < 4; ++nt) {
                const float a0 = acc0[nt][r] + b0v[r];
                const float a1 = acc1[nt][r] + b1v[r];
                const float r0 = __shfl_xor(a0, 32);        // h <-> h+2
                const float r1 = __shfl_xor(a1, 32);
                const float j0 = lower ? a0 : r0;           // rows t, t+8, t+16, t+24
                const float j1 = lower ? r0 : a0;
                const float j2 = lower ? a1 : r1;
                const float j3 = lower ? r1 : a1;
                if ((nt & 1) == (h >> 1)) {                 // balanced output split
                    const int a = ((2 * nt + beta) * 4 + (w >> 1)) * 8 + (w & 1) * 4;
                    *(uint2*)(kw + tb + (size_t)((p * 8 + t) * 256 + a)) =
                        make_uint2(pkbf(j0, j1), pkbf(j2, j3));
                }
            }
        }
    }

    // ================= V : wave owns m-tiles {M, M+2} =================
    const int M = ((w >> 1) << 2) | (w & 1);
#pragma unroll
    for (int kk = 0; kk < 8; ++kk) {
        wf0[kk] = wsv[((2 * 16 + M) * 8 + kk) * 64 + l];
        wf1[kk] = wsv[((2 * 16 + M + 2) * 8 + kk) * 64 + l];
    }
#pragma unroll
    for (int nt = 0; nt < 4; ++nt) { acc0[nt] = (f32x4){0,0,0,0}; acc1[nt] = (f32x4){0,0,0,0}; }
#pragma unroll
    for (int nt = 0; nt < 4; ++nt)
#pragma unroll
        for (int kk = 0; kk < 8; ++kk) {
            const short8 bx = *(const short8*)&Xs[nt * 16 + c15][kk * 32 + h * 8];
            acc0[nt] = MFMA16(wf0[kk], bx, acc0[nt]);
            acc1[nt] = MFMA16(wf1[kk], bx, acc1[nt]);
        }
    {
        const float4 b0 = *(const float4*)&bv[M * 16 + 4 * h];
        const float4 b1 = *(const float4*)&bv[(M + 2) * 16 + 4 * h];
        const float b0v[4] = {b0.x, b0.y, b0.z, b0.w}, b1v[4] = {b1.x, b1.y, b1.z, b1.w};
        const int tp2 = 2 * (w >> 1);                       // t-pair base
#pragma unroll
        for (int r = 0; r < 4; ++r)
#pragma unroll
            for (int nt = 0; nt < 4; ++nt) {
                // t-pair (2tp, 2tp+1) lives in (acc0, acc1) of THIS lane
                const unsigned wd = pkbf(acc0[nt][r] + b0v[r], acc1[nt][r] + b1v[r]);
                const int aV = (16 * (w & 1) + 4 * h + r) * 8 + 2 * nt + beta;
                *(unsigned*)(vw + tb + (size_t)((p * 256 + aV) * 8 + tp2)) = wd;
            }
    }
}

// ---------------- kernel B: attention (QKVw -> out), UNCHANGED from R5 ----------------
__global__ __launch_bounds__(256, 4)
void attnB(const bf16* __restrict__ qw, const bf16* __restrict__ kw,
           const bf16* __restrict__ vw, float* __restrict__ out,
           int b_base, int nwg)
{
    __shared__ __align__(16) bf16 PL[16][9][8];   // [px][s][t] probs, padded rows

    const int tid = (int)threadIdx.x;
    const int l = tid & 63, w = tid >> 6, h = l >> 4, c15 = l & 15;
    const int chunk = nwg >> 3;
    const int wg = ((int)blockIdx.x & 7) * chunk + ((int)blockIdx.x >> 3);
    const int b = b_base + (wg >> 8), pt16 = wg & 255;
    const int lt8 = (wg >> 8) * 512 + pt16 * 2;     // local tile8 base
    const size_t p16 = (size_t)pt16 * 16;

    // ---- scores + softmax (wave w owns pixel-pair tiles 2w, 2w+1) ----
    const int pxr = c15 >> 3, st = c15 & 7;
#pragma unroll
    for (int ti = 0; ti < 2; ++ti) {
        const int tau = w * 2 + ti;
        const int px = 2 * tau + pxr;
        const size_t tb = (size_t)(lt8 + (px >> 3)) * 16384 + (size_t)(((px & 7) * 8 + st) * 256);
        const short8* Qb = (const short8*)(qw + tb);
        const short8* Kb = (const short8*)(kw + tb);
        f32x4 sacc = {0.f, 0.f, 0.f, 0.f};
#pragma unroll
        for (int kk = 0; kk < 8; ++kk)
            sacc = MFMA16(Qb[kk * 4 + h], Kb[kk * 4 + h], sacc);
        const bool valid = ((h >> 1) == pxr);
        const int pxo = 2 * tau + (h >> 1);
#pragma unroll
        for (int r = 0; r < 4; ++r) {
            const float S = sacc[r] * 0.0625f;
            float m = S;
            m = fmaxf(m, __shfl_xor(m, 1));
            m = fmaxf(m, __shfl_xor(m, 2));
            m = fmaxf(m, __shfl_xor(m, 4));
            const float e = __expf(S - m);
            float sm = e;
            sm += __shfl_xor(sm, 1);
            sm += __shfl_xor(sm, 2);
            sm += __shfl_xor(sm, 4);
            if (valid) PL[pxo][4 * (h & 1) + r][st] = __float2bfloat16(e / sm);
        }
    }
    __syncthreads();

    // ---- PV: D rows = (s-half, 4 px), cols = a; pacc = 4 consecutive px ----
    const int pxl = c15 & 3, sl = c15 >> 2;
    const short8 zv = {0, 0, 0, 0, 0, 0, 0, 0};
#pragma unroll
    for (int sg = 0; sg < 2; ++sg) {
        short8 pa[4];
#pragma unroll
        for (int q = 0; q < 4; ++q) {
            const short8 t = *(const short8*)&PL[q * 4 + pxl][sg * 4 + sl][0];
            pa[q] = (h == pxl) ? t : zv;
        }
        const int s = sg * 4 + h;
#pragma unroll
        for (int ci = 0; ci < 4; ++ci) {
            const int a = (w * 4 + ci) * 16 + c15;
            const int s2 = a & 7, a2 = (s << 5) | (a >> 3);
            float* orow = &out[((size_t)((b * 8 + s2) * 256 + a2)) * 4096 + p16];
#pragma unroll
            for (int q = 0; q < 4; ++q) {
                const int px = q * 4 + h;
                const size_t vo = (size_t)(lt8 + (px >> 3)) * 16384 +
                                  (size_t)((((px & 7) << 8) + a) << 3);
                const short8 vb = *(const short8*)(vw + vo);
                f32x4 pacc = {0.f, 0.f, 0.f, 0.f};
                pacc = MFMA16(pa[q], vb, pacc);
                *(f32x4*)&orow[q * 4] = pacc;   // 16B store, 4 consecutive pixels
            }
        }
    }
}

extern "C" void kernel_launch(void* const* d_in, const int* in_sizes, int n_in,
                              void* d_out, int out_size, void* d_ws, size_t ws_size,
                              hipStream_t stream) {
    (void)in_sizes; (void)n_in; (void)out_size;
    const float* x  = (const float*)d_in[0];
    const float* wq = (const float*)d_in[1];
    const float* bq = (const float*)d_in[2];
    const float* wk = (const float*)d_in[3];
    const float* bk = (const float*)d_in[4];
    const float* wv = (const float*)d_in[5];
    const float* bv = (const float*)d_in[6];
    float* out = (float*)d_out;

    bf16* wsW = (bf16*)d_ws;                 // 196608 el = 384 KB
    bf16* qwp = wsW + 196608;

    int nb = 4;                              // batches per A/B pass (ws-adaptive)
    while (nb > 1 && ws_size < 2ull * (196608ull + 3ull * (size_t)nb * 512 * 16384))
        nb >>= 1;
    const size_t span = (size_t)nb * 512 * 16384;
    bf16* kwp = qwp + span;
    bf16* vwp = kwp + span;

    hipLaunchKernelGGL(prep_w, dim3(96), dim3(256), 0, stream, wq, wk, wv, wsW);
    for (int b0 = 0; b0 < 4; b0 += nb) {
        hipLaunchKernelGGL(projA, dim3(nb * 512), dim3(512), 0, stream,
                           x, bq, bk, bv, wsW, qwp, kwp, vwp, b0, nb * 512);
        hipLaunchKernelGGL(attnB, dim3(nb * 256), dim3(256), 0, stream,
                           qwp, kwp, vwp, out, b0, nb * 256);
    }
}

// Round 7
// 183.776 us; speedup vs baseline: 1.5765x; 1.5765x over previous
//
#include <hip/hip_runtime.h>
#include <hip/hip_bf16.h>

typedef __hip_bfloat16 bf16;
typedef __attribute__((ext_vector_type(8))) short short8;
typedef __attribute__((ext_vector_type(4))) float f32x4;

#define MFMA16(A, B, C) __builtin_amdgcn_mfma_f32_16x16x32_bf16((A), (B), (C), 0, 0, 0)

__device__ __forceinline__ unsigned pkbf(float a, float b) {
    __hip_bfloat162 h2 = __float22bfloat162_rn(make_float2(a, b));
    return *reinterpret_cast<unsigned*>(&h2);
}

// ---------------- prep: W fp32 -> frag-major bf16 in ws (unchanged, verified) ----------------
__global__ __launch_bounds__(256) void prep_w(const float* __restrict__ wq,
                                              const float* __restrict__ wk,
                                              const float* __restrict__ wv,
                                              bf16* __restrict__ wsW)
{
    const int t = (int)blockIdx.x * 256 + (int)threadIdx.x;   // 0..24575
    const int lane = t & 63, kk = (t >> 6) & 7, mt = (t >> 9) & 15, proj = t >> 13;
    const float* W = (proj == 0) ? wq : ((proj == 1) ? wk : wv);
    const int row = mt * 16 + (lane & 15);
    const int col = kk * 32 + (lane >> 4) * 8;
    bf16* dst = wsW + (size_t)t * 8;
#pragma unroll
    for (int j = 0; j < 8; ++j) dst[j] = __float2bfloat16(W[row * 256 + col + j]);
}

// LDS byte map:
//   XC [64 col][64 c] bf16 @0      (8192)   swz ^((row&7)<<4)     ; dead after pass2
//   QL [8px][8s][264a] bf16 @8192  (33792)  swz ^((px&7)<<4)      ; VL aliases
//   KL [8px][8t][264a] bf16 @41984 (33792)  swz ^((px&7)<<4)
//   PL [8px][9][8] bf16 @75776     (1152)
//   VL [8px][256a][8t] bf16 @8192  (32768)  swz ^(((px^(a>>3))&7)<<4)
#define QLB 8192
#define KLB 41984
#define VLB 8192
#define PLB 75776

__global__ __launch_bounds__(512, 4)
void fused_sa(const float* __restrict__ x,
              const float* __restrict__ bq, const float* __restrict__ bk,
              const float* __restrict__ bv,
              const bf16* __restrict__ wsW,
              float* __restrict__ out)
{
    __shared__ __align__(16) char SM[76928];

    const int tid = (int)threadIdx.x;
    const int l = tid & 63, w = tid >> 6, h = l >> 4, c15 = l & 15;
    const int p = c15 & 7, beta = c15 >> 3;

    const int wg = ((int)blockIdx.x & 7) * 256 + ((int)blockIdx.x >> 3);
    const int b = wg >> 9, p0 = (wg & 511) * 8;

    const short8* wsv = (const short8*)wsW;
    const int p2 = (l & 3) * 2, chi = l >> 2;    // wave w stages s'=w
    const size_t xbase = ((size_t)((b * 8 + w) * 256)) * 4096 + p0 + p2;

    // =============== PASS 1: Q,K projections over 4 K-chunks ===============
    f32x4 aQ0[4] = {}, aQ1[4] = {}, aK0[4] = {}, aK1[4] = {};
    {
        float2 xr[4];
#pragma unroll
        for (int i = 0; i < 4; ++i)
            xr[i] = *(const float2*)&x[xbase + (size_t)(i * 16 + chi) * 4096];

        for (int cc = 0; cc < 4; ++cc) {
            if (cc) __syncthreads();
#pragma unroll
            for (int i = 0; i < 4; ++i) {
                const int c = i * 16 + chi;
                const int r0 = w * 8 + p2, r1 = r0 + 1;
                *(bf16*)(SM + ((r0 * 128 + c * 2) ^ ((r0 & 7) << 4))) = __float2bfloat16(xr[i].x);
                *(bf16*)(SM + ((r1 * 128 + c * 2) ^ ((r1 & 7) << 4))) = __float2bfloat16(xr[i].y);
            }
            if (cc < 3) {
#pragma unroll
                for (int i = 0; i < 4; ++i)
                    xr[i] = *(const float2*)&x[xbase + (size_t)((cc + 1) * 64 + i * 16 + chi) * 4096];
            }
            __syncthreads();
#pragma unroll
            for (int k2 = 0; k2 < 2; ++k2) {
                const int kg = cc * 2 + k2;
                const short8 fQ0 = wsv[((0 * 16 + 2 * w)     * 8 + kg) * 64 + l];
                const short8 fQ1 = wsv[((0 * 16 + 2 * w + 1) * 8 + kg) * 64 + l];
                const short8 fK0 = wsv[((1 * 16 + 2 * w)     * 8 + kg) * 64 + l];
                const short8 fK1 = wsv[((1 * 16 + 2 * w + 1) * 8 + kg) * 64 + l];
#pragma unroll
                for (int nt = 0; nt < 4; ++nt) {
                    const int row = nt * 16 + c15;
                    const short8 bx = *(const short8*)(SM +
                        ((row * 128 + (k2 * 32 + h * 8) * 2) ^ ((row & 7) << 4)));
                    aQ0[nt] = MFMA16(fQ0, bx, aQ0[nt]);
                    aQ1[nt] = MFMA16(fQ1, bx, aQ1[nt]);
                    aK0[nt] = MFMA16(fK0, bx, aK0[nt]);
                    aK1[nt] = MFMA16(fK1, bx, aK1[nt]);
                }
            }
        }
    }

    // ---- Q epilogue -> QL (R6-verified shuffle-pack) ----
    {
        const float4 b0 = *(const float4*)&bq[(2 * w) * 16 + 4 * h];
        const float4 b1 = *(const float4*)&bq[(2 * w + 1) * 16 + 4 * h];
        const float b0v[4] = {b0.x, b0.y, b0.z, b0.w}, b1v[4] = {b1.x, b1.y, b1.z, b1.w};
#pragma unroll
        for (int r = 0; r < 4; ++r) {
            unsigned wds[4];
#pragma unroll
            for (int nt = 0; nt < 4; ++nt) {
                const float a0 = aQ0[nt][r] + b0v[r];
                const float a1 = aQ1[nt][r] + b1v[r];
                const float send = beta ? a0 : a1;
                const float recv = __shfl_xor(send, 8);
                const float own  = beta ? a1 : a0;
                wds[nt] = beta ? pkbf(recv, own) : pkbf(own, recv);
            }
            const int G = 16 * beta + 4 * h + r;
            *(uint4*)(SM + QLB + ((p * 4224 + w * 528 + G * 16) ^ ((p & 7) << 4))) =
                make_uint4(wds[0], wds[1], wds[2], wds[3]);
        }
    }
    // ---- K epilogue -> KL (R6-verified) ----
    {
        const float4 b0 = *(const float4*)&bk[(2 * w) * 16 + 4 * h];
        const float4 b1 = *(const float4*)&bk[(2 * w + 1) * 16 + 4 * h];
        const float b0v[4] = {b0.x, b0.y, b0.z, b0.w}, b1v[4] = {b1.x, b1.y, b1.z, b1.w};
        const bool lower = (h < 2);
#pragma unroll
        for (int r = 0; r < 4; ++r) {
            const int t = 4 * (h & 1) + r;
#pragma unroll
            for (int nt = 0; nt < 4; ++nt) {
                const float a0 = aK0[nt][r] + b0v[r];
                const float a1 = aK1[nt][r] + b1v[r];
                const float r0 = __shfl_xor(a0, 32);
                const float r1 = __shfl_xor(a1, 32);
                const float j0 = lower ? a0 : r0;
                const float j1 = lower ? r0 : a0;
                const float j2 = lower ? a1 : r1;
                const float j3 = lower ? r1 : a1;
                if ((nt & 1) == (h >> 1)) {
                    const int a = ((2 * nt + beta) * 4 + (w >> 1)) * 8 + (w & 1) * 4;
                    *(uint2*)(SM + KLB + ((p * 4224 + t * 528 + a * 2) ^ ((p & 7) << 4))) =
                        make_uint2(pkbf(j0, j1), pkbf(j2, j3));
                }
            }
        }
    }
    __syncthreads();   // QL/KL ready

    // ---- scores + softmax (waves 0-3; R2-verified) ----
    if (w < 4) {
        const int q = w, pxr = c15 >> 3, st = c15 & 7;
        const int px = 2 * q + pxr;
        f32x4 sacc = {0.f, 0.f, 0.f, 0.f};
#pragma unroll
        for (int kk = 0; kk < 8; ++kk) {
            const int off = (px * 4224 + st * 528 + (kk * 32 + h * 8) * 2) ^ ((px & 7) << 4);
            const short8 qa = *(const short8*)(SM + QLB + off);
            const short8 kb = *(const short8*)(SM + KLB + off);
            sacc = MFMA16(qa, kb, sacc);
        }
        const bool valid = ((h >> 1) == pxr);
        const int pxo = 2 * q + (h >> 1);
        bf16 (*PL)[9][8] = (bf16 (*)[9][8])(SM + PLB);
#pragma unroll
        for (int r = 0; r < 4; ++r) {
            const float S = sacc[r] * 0.0625f;
            float m = S;
            m = fmaxf(m, __shfl_xor(m, 1));
            m = fmaxf(m, __shfl_xor(m, 2));
            m = fmaxf(m, __shfl_xor(m, 4));
            const float e = __expf(S - m);
            float sm = e;
            sm += __shfl_xor(sm, 1);
            sm += __shfl_xor(sm, 2);
            sm += __shfl_xor(sm, 4);
            if (valid) PL[pxo][4 * (h & 1) + r][st] = __float2bfloat16(e / sm);
        }
    }
    __syncthreads();   // scores done reading QL; PL ready; VL region free

    // =============== PASS 2: V projection (restage X chunks; L2-hot) ===============
    const int Mv = ((w >> 1) << 2) | (w & 1);
    f32x4 aV0[4] = {}, aV1[4] = {};
    {
        float2 xr[4];
#pragma unroll
        for (int i = 0; i < 4; ++i)
            xr[i] = *(const float2*)&x[xbase + (size_t)(i * 16 + chi) * 4096];

        for (int cc = 0; cc < 4; ++cc) {
            __syncthreads();    // prev chunk readers done (and, for cc=0, XC free)
#pragma unroll
            for (int i = 0; i < 4; ++i) {
                const int c = i * 16 + chi;
                const int r0 = w * 8 + p2, r1 = r0 + 1;
                *(bf16*)(SM + ((r0 * 128 + c * 2) ^ ((r0 & 7) << 4))) = __float2bfloat16(xr[i].x);
                *(bf16*)(SM + ((r1 * 128 + c * 2) ^ ((r1 & 7) << 4))) = __float2bfloat16(xr[i].y);
            }
            if (cc < 3) {
#pragma unroll
                for (int i = 0; i < 4; ++i)
                    xr[i] = *(const float2*)&x[xbase + (size_t)((cc + 1) * 64 + i * 16 + chi) * 4096];
            }
            __syncthreads();
#pragma unroll
            for (int k2 = 0; k2 < 2; ++k2) {
                const int kg = cc * 2 + k2;
                const short8 fV0 = wsv[((2 * 16 + Mv)     * 8 + kg) * 64 + l];
                const short8 fV1 = wsv[((2 * 16 + Mv + 2) * 8 + kg) * 64 + l];
#pragma unroll
                for (int nt = 0; nt < 4; ++nt) {
                    const int row = nt * 16 + c15;
                    const short8 bx = *(const short8*)(SM +
                        ((row * 128 + (k2 * 32 + h * 8) * 2) ^ ((row & 7) << 4)));
                    aV0[nt] = MFMA16(fV0, bx, aV0[nt]);
                    aV1[nt] = MFMA16(fV1, bx, aV1[nt]);
                }
            }
        }
    }

    // ---- V epilogue -> VL (R6-verified zero-shuffle map) ----
    {
        const float4 b0 = *(const float4*)&bv[Mv * 16 + 4 * h];
        const float4 b1 = *(const float4*)&bv[(Mv + 2) * 16 + 4 * h];
        const float b0v[4] = {b0.x, b0.y, b0.z, b0.w}, b1v[4] = {b1.x, b1.y, b1.z, b1.w};
        const int tp2 = 2 * (w >> 1);
#pragma unroll
        for (int r = 0; r < 4; ++r)
#pragma unroll
            for (int nt = 0; nt < 4; ++nt) {
                const unsigned wd = pkbf(aV0[nt][r] + b0v[r], aV1[nt][r] + b1v[r]);
                const int aV = (16 * (w & 1) + 4 * h + r) * 8 + 2 * nt + beta;
                *(unsigned*)(SM + VLB +
                    ((p * 4096 + aV * 16 + tp2 * 2) ^ (((p ^ (aV >> 3)) & 7) << 4))) = wd;
            }
    }
    __syncthreads();   // VL + PL ready

    // ---- PV (attnB-verified structure, 8 px) -> coalesced float4 stores ----
    {
        bf16 (*PL)[9][8] = (bf16 (*)[9][8])(SM + PLB);
        const int pxl = c15 & 3, sl = c15 >> 2;
        const short8 zv = {0, 0, 0, 0, 0, 0, 0, 0};
#pragma unroll
        for (int sg = 0; sg < 2; ++sg) {
            short8 pa[2];
#pragma unroll
            for (int q = 0; q < 2; ++q) {
                const short8 t8 = *(const short8*)&PL[q * 4 + pxl][sg * 4 + sl][0];
                pa[q] = (h == pxl) ? t8 : zv;
            }
            const int s = sg * 4 + h;
#pragma unroll
            for (int ci = 0; ci < 2; ++ci) {
                const int a = (2 * w + ci) * 16 + c15;
                const int s2 = a & 7, a2 = (s << 5) | (a >> 3);
#pragma unroll
                for (int q = 0; q < 2; ++q) {
                    const int px = q * 4 + h;
                    const short8 vb = *(const short8*)(SM + VLB +
                        ((px * 4096 + a * 16) ^ (((px ^ (a >> 3)) & 7) << 4)));
                    f32x4 pacc = {0.f, 0.f, 0.f, 0.f};
                    pacc = MFMA16(pa[q], vb, pacc);
                    *(f32x4*)&out[((size_t)((b * 8 + s2) * 256 + a2)) * 4096 + p0 + q * 4] = pacc;
                }
            }
        }
    }
}

extern "C" void kernel_launch(void* const* d_in, const int* in_sizes, int n_in,
                              void* d_out, int out_size, void* d_ws, size_t ws_size,
                              hipStream_t stream) {
    (void)in_sizes; (void)n_in; (void)out_size; (void)ws_size;
    const float* x  = (const float*)d_in[0];
    const float* wq = (const float*)d_in[1];
    const float* bq = (const float*)d_in[2];
    const float* wk = (const float*)d_in[3];
    const float* bk = (const float*)d_in[4];
    const float* wv = (const float*)d_in[5];
    const float* bv = (const float*)d_in[6];
    float* out = (float*)d_out;
    bf16* wsW  = (bf16*)d_ws;   // 393,216 bytes

    hipLaunchKernelGGL(prep_w, dim3(96), dim3(256), 0, stream, wq, wk, wv, wsW);
    hipLaunchKernelGGL(fused_sa, dim3(2048), dim3(512), 0, stream,
                       x, bq, bk, bv, wsW, out);
}